// Round 1
// baseline (6208.769 us; speedup 1.0000x reference)
//
#include <hip/hip_runtime.h>
#include <hip/hip_bf16.h>

// ---- problem constants ----
constexpr int CB   = 4;     // batch
constexpr int CS   = 512;   // seq
constexpr int CF   = 16;    // feat
constexpr int CD   = 512;   // model dim
constexpr int CH   = 8;     // heads
constexpr int CL   = 6;     // layers
constexpr int CDFF = 2048;  // ff dim
constexpr int CNC  = 12;    // classes
constexpr int CRPH = 64;    // relpos hidden
constexpr int CDH  = 64;    // head dim

// ---------------------------------------------------------------------------
// standardize x[...,ch] over seq axis -> t (ch=0), f (ch=1); shape (B,S)
__global__ void k_standardize(const float* __restrict__ x, float* __restrict__ ts,
                              float* __restrict__ fs) {
    int b = blockIdx.x;
    int ch = blockIdx.y;           // 0 -> t, 1 -> f
    int tid = threadIdx.x;         // 256 threads, each covers 2 elements
    __shared__ float red[256];

    float v0 = x[(b * CS + tid) * CF + ch];
    float v1 = x[(b * CS + tid + 256) * CF + ch];

    red[tid] = v0 + v1;
    __syncthreads();
    for (int w = 128; w > 0; w >>= 1) {
        if (tid < w) red[tid] += red[tid + w];
        __syncthreads();
    }
    float mean = red[0] * (1.0f / CS);
    __syncthreads();

    float d0 = v0 - mean, d1 = v1 - mean;
    red[tid] = d0 * d0 + d1 * d1;
    __syncthreads();
    for (int w = 128; w > 0; w >>= 1) {
        if (tid < w) red[tid] += red[tid + w];
        __syncthreads();
    }
    float inv = rsqrtf(red[0] * (1.0f / CS) + 1e-6f);

    float* o = (ch == 0) ? ts : fs;
    o[b * CS + tid]       = d0 * inv;
    o[b * CS + tid + 256] = d1 * inv;
}

// ---------------------------------------------------------------------------
// relpos bias: per (b,i,j) run MLP(2->64->8), clip, write (B,H,S,S)
__global__ void k_relpos(const float* __restrict__ ts, const float* __restrict__ fs,
                         const float* __restrict__ w1, const float* __restrict__ b1,
                         const float* __restrict__ w2, const float* __restrict__ b2,
                         float* __restrict__ bias) {
    int idx = blockIdx.x * 256 + threadIdx.x;   // B*S*S = 1,048,576
    int j = idx & (CS - 1);
    int i = (idx >> 9) & (CS - 1);
    int b = idx >> 18;

    float dt = ts[b * CS + i] - ts[b * CS + j];
    float df = fs[b * CS + i] - fs[b * CS + j];

    float acc[CH];
#pragma unroll
    for (int h = 0; h < CH; h++) acc[h] = b2[h];

    for (int r = 0; r < CRPH; r++) {
        float hd = fmaxf(w1[r * 2] * dt + w1[r * 2 + 1] * df + b1[r], 0.0f);
#pragma unroll
        for (int h = 0; h < CH; h++) acc[h] += w2[h * CRPH + r] * hd;
    }
#pragma unroll
    for (int h = 0; h < CH; h++) {
        float v = fminf(fmaxf(acc[h], -5.0f), 5.0f);
        bias[((b * CH + h) * CS + i) * CS + j] = v;
    }
}

// ---------------------------------------------------------------------------
// embed: h[m][d] = sum_f x[m][f]*W[d][f] + b[d]
__global__ void k_embed(const float* __restrict__ x, const float* __restrict__ w,
                        const float* __restrict__ bvec, float* __restrict__ h) {
    int idx = blockIdx.x * 256 + threadIdx.x;   // B*S*D
    int d = idx & (CD - 1);
    int m = idx >> 9;
    const float* xr = x + m * CF;
    const float* wr = w + d * CF;
    float acc = bvec[d];
#pragma unroll
    for (int f = 0; f < CF; f++) acc += xr[f] * wr[f];
    h[idx] = acc;
}

// ---------------------------------------------------------------------------
// NT GEMM: C[M][N] = A[M][K] @ W[N][K]^T + bias[N]  (optional relu)
// tiles: 64x64x16, 256 threads, 4x4 per thread
template <int RELU>
__global__ void k_gemm(const float* __restrict__ A, const float* __restrict__ W,
                       const float* __restrict__ bias, float* __restrict__ C,
                       int M, int N, int K) {
    constexpr int BM = 64, BN = 64, BK = 16;
    __shared__ float As[BK][BM + 1];
    __shared__ float Bs[BK][BN + 1];

    int tid = threadIdx.x;
    int bn = blockIdx.x * BN;
    int bm = blockIdx.y * BM;
    int tx = tid & 15, ty = tid >> 4;

    float acc[4][4] = {};

    for (int k0 = 0; k0 < K; k0 += BK) {
#pragma unroll
        for (int t = 0; t < 4; t++) {
            int e = tid + t * 256;
            int r = e >> 4, c = e & 15;
            As[c][r] = A[(bm + r) * K + k0 + c];
            Bs[c][r] = W[(bn + r) * K + k0 + c];
        }
        __syncthreads();
#pragma unroll
        for (int k = 0; k < BK; k++) {
            float a[4], bb[4];
#pragma unroll
            for (int i = 0; i < 4; i++) a[i] = As[k][ty * 4 + i];
#pragma unroll
            for (int j = 0; j < 4; j++) bb[j] = Bs[k][tx * 4 + j];
#pragma unroll
            for (int i = 0; i < 4; i++)
#pragma unroll
                for (int j = 0; j < 4; j++) acc[i][j] += a[i] * bb[j];
        }
        __syncthreads();
    }

#pragma unroll
    for (int i = 0; i < 4; i++) {
        int row = bm + ty * 4 + i;
#pragma unroll
        for (int j = 0; j < 4; j++) {
            int col = bn + tx * 4 + j;
            float v = acc[i][j] + bias[col];
            if (RELU) v = fmaxf(v, 0.0f);
            C[(long)row * N + col] = v;
        }
    }
}

// ---------------------------------------------------------------------------
// attention for one (b,h,i) row: scores = q.k*scale + bias -> softmax -> .v
__global__ void k_attn(const float* __restrict__ qkv, const float* __restrict__ bias,
                       float* __restrict__ att) {
    int blk = blockIdx.x;               // B*H*S blocks
    int i = blk & (CS - 1);
    int h = (blk >> 9) & (CH - 1);
    int b = blk >> 12;
    int tid = threadIdx.x;              // 256

    __shared__ float qs[CDH];
    __shared__ float p[CS];
    __shared__ float red[256];

    const float scale = 0.125f;         // 1/sqrt(64)

    const float* qrow = qkv + ((long)(b * CS + i) * 3 * CD) + h * CDH;
    if (tid < CDH) qs[tid] = qrow[tid];
    __syncthreads();

    const float* biasrow = bias + ((long)(b * CH + h) * CS + i) * CS;
    for (int j = tid; j < CS; j += 256) {
        const float* krow = qkv + ((long)(b * CS + j) * 3 * CD) + CD + h * CDH;
        float acc = 0.0f;
#pragma unroll
        for (int d = 0; d < CDH; d++) acc += qs[d] * krow[d];
        p[j] = acc * scale + biasrow[j];
    }
    __syncthreads();

    // row max
    float m = -1e30f;
    for (int j = tid; j < CS; j += 256) m = fmaxf(m, p[j]);
    red[tid] = m;
    __syncthreads();
    for (int w = 128; w > 0; w >>= 1) {
        if (tid < w) red[tid] = fmaxf(red[tid], red[tid + w]);
        __syncthreads();
    }
    m = red[0];
    __syncthreads();

    // exp + sum
    float sum = 0.0f;
    for (int j = tid; j < CS; j += 256) {
        float e = expf(p[j] - m);
        p[j] = e;
        sum += e;
    }
    red[tid] = sum;
    __syncthreads();
    for (int w = 128; w > 0; w >>= 1) {
        if (tid < w) red[tid] += red[tid + w];
        __syncthreads();
    }
    float inv = 1.0f / red[0];
    __syncthreads();

    // o[d] = sum_j p[j] * v[j][d]   (4 partial slabs of 128 j's)
    int d = tid & 63;
    int part = tid >> 6;
    float acc = 0.0f;
    const float* vbase = qkv + 2 * CD + h * CDH + d;
    for (int j = part * 128; j < part * 128 + 128; j++) {
        acc += p[j] * vbase[(long)(b * CS + j) * 3 * CD];
    }
    red[tid] = acc;
    __syncthreads();
    if (tid < 64) {
        float o = (red[tid] + red[tid + 64] + red[tid + 128] + red[tid + 192]) * inv;
        att[((long)(b * CS + i) * CD) + h * CDH + tid] = o;
    }
}

// ---------------------------------------------------------------------------
// fused residual + layernorm (in place on hbuf): h = LN(h + add) * s + b
__global__ void k_ln(float* __restrict__ hbuf, const float* __restrict__ addbuf,
                     const float* __restrict__ s, const float* __restrict__ bvec) {
    int row = blockIdx.x;      // B*S rows
    int tid = threadIdx.x;     // 256, 2 elements each (D=512)
    __shared__ float red[256];

    float v0 = hbuf[(long)row * CD + tid]       + addbuf[(long)row * CD + tid];
    float v1 = hbuf[(long)row * CD + tid + 256] + addbuf[(long)row * CD + tid + 256];

    red[tid] = v0 + v1;
    __syncthreads();
    for (int w = 128; w > 0; w >>= 1) {
        if (tid < w) red[tid] += red[tid + w];
        __syncthreads();
    }
    float mean = red[0] * (1.0f / CD);
    __syncthreads();

    float d0 = v0 - mean, d1 = v1 - mean;
    red[tid] = d0 * d0 + d1 * d1;
    __syncthreads();
    for (int w = 128; w > 0; w >>= 1) {
        if (tid < w) red[tid] += red[tid + w];
        __syncthreads();
    }
    float inv = rsqrtf(red[0] * (1.0f / CD) + 1e-5f);

    hbuf[(long)row * CD + tid]       = d0 * inv * s[tid] + bvec[tid];
    hbuf[(long)row * CD + tid + 256] = d1 * inv * s[tid + 256] + bvec[tid + 256];
}

// ---------------------------------------------------------------------------
// mean pool over seq + final fc: out[b][c] = (1/S sum_s h[b][s][:]) . fcw[c] + fcb[c]
__global__ void k_poolfc(const float* __restrict__ h, const float* __restrict__ fcw,
                         const float* __restrict__ fcb, float* __restrict__ out) {
    int b = blockIdx.x;
    int tid = threadIdx.x;
    __shared__ float rep[CD];

    for (int d = tid; d < CD; d += 256) {
        float acc = 0.0f;
        for (int s0 = 0; s0 < CS; s0++) acc += h[((long)(b * CS + s0)) * CD + d];
        rep[d] = acc * (1.0f / CS);
    }
    __syncthreads();
    if (tid < CNC) {
        float acc = fcb[tid];
        for (int d = 0; d < CD; d++) acc += rep[d] * fcw[tid * CD + d];
        out[b * CNC + tid] = acc;
    }
}

// ---------------------------------------------------------------------------
extern "C" void kernel_launch(void* const* d_in, const int* in_sizes, int n_in,
                              void* d_out, int out_size, void* d_ws, size_t ws_size,
                              hipStream_t stream) {
    const float* x   = (const float*)d_in[0];
    const float* rw1 = (const float*)d_in[1];
    const float* rb1 = (const float*)d_in[2];
    const float* rw2 = (const float*)d_in[3];
    const float* rb2 = (const float*)d_in[4];
    const float* emw = (const float*)d_in[5];
    const float* emb = (const float*)d_in[6];
    const float* aiw = (const float*)d_in[7];
    const float* aib = (const float*)d_in[8];
    const float* aow = (const float*)d_in[9];
    const float* aob = (const float*)d_in[10];
    const float* f1w = (const float*)d_in[11];
    const float* f1b = (const float*)d_in[12];
    const float* f2w = (const float*)d_in[13];
    const float* f2b = (const float*)d_in[14];
    const float* l1s = (const float*)d_in[15];
    const float* l1b = (const float*)d_in[16];
    const float* l2s = (const float*)d_in[17];
    const float* l2b = (const float*)d_in[18];
    const float* fcw = (const float*)d_in[19];
    const float* fcb = (const float*)d_in[20];
    float* out = (float*)d_out;

    float* w = (float*)d_ws;
    float* ts   = w; w += CB * CS;
    float* fs   = w; w += CB * CS;
    float* bias = w; w += (size_t)CB * CH * CS * CS;   // 8.4M
    float* hbuf = w; w += (size_t)CB * CS * CD;        // 1.05M
    float* qkv  = w; w += (size_t)CB * CS * 3 * CD;    // 3.1M
    float* att  = w; w += (size_t)CB * CS * CD;
    float* tmp  = w; w += (size_t)CB * CS * CD;
    float* ffb  = w; w += (size_t)CB * CS * CDFF;      // 4.2M

    const int M = CB * CS;   // 2048 rows

    k_standardize<<<dim3(CB, 2), 256, 0, stream>>>(x, ts, fs);
    k_relpos<<<(CB * CS * CS) / 256, 256, 0, stream>>>(ts, fs, rw1, rb1, rw2, rb2, bias);
    k_embed<<<(M * CD) / 256, 256, 0, stream>>>(x, emw, emb, hbuf);

    for (int l = 0; l < CL; l++) {
        k_gemm<0><<<dim3(3 * CD / 64, M / 64), 256, 0, stream>>>(
            hbuf, aiw + (size_t)l * 3 * CD * CD, aib + (size_t)l * 3 * CD, qkv, M, 3 * CD, CD);
        k_attn<<<CB * CH * CS, 256, 0, stream>>>(qkv, bias, att);
        k_gemm<0><<<dim3(CD / 64, M / 64), 256, 0, stream>>>(
            att, aow + (size_t)l * CD * CD, aob + (size_t)l * CD, tmp, M, CD, CD);
        k_ln<<<M, 256, 0, stream>>>(hbuf, tmp, l1s + (size_t)l * CD, l1b + (size_t)l * CD);
        k_gemm<1><<<dim3(CDFF / 64, M / 64), 256, 0, stream>>>(
            hbuf, f1w + (size_t)l * CDFF * CD, f1b + (size_t)l * CDFF, ffb, M, CDFF, CD);
        k_gemm<0><<<dim3(CD / 64, M / 64), 256, 0, stream>>>(
            ffb, f2w + (size_t)l * CD * CDFF, f2b + (size_t)l * CD, tmp, M, CD, CDFF);
        k_ln<<<M, 256, 0, stream>>>(hbuf, tmp, l2s + (size_t)l * CD, l2b + (size_t)l * CD);
    }

    k_poolfc<<<CB, 256, 0, stream>>>(hbuf, fcw, fcb, out);
}

// Round 2
// 740.192 us; speedup vs baseline: 8.3881x; 8.3881x over previous
//
#include <hip/hip_runtime.h>
#include <hip/hip_bf16.h>
#include <stdint.h>

using short8 = __attribute__((ext_vector_type(8))) short;
using f32x4  = __attribute__((ext_vector_type(4))) float;
using bf16   = __hip_bfloat16;

constexpr int CB=4, CS=512, CF=16, CD=512, CH=8, CL=6, CDFF=2048, CNC=12, CRPH=64, CDH=64;

// ---------------------------------------------------------------------------
__device__ inline void gload_lds16(const void* g, void* l) {
    __builtin_amdgcn_global_load_lds((const __attribute__((address_space(1))) void*)g,
                                     (__attribute__((address_space(3))) void*)l, 16, 0, 0);
}

// Shared MFMA GEMM core: C[BM][BN] += A[BM][K] * W[BN][K]^T, bf16 in, f32 acc.
// LDS linear [rows][32] bf16 (64 B/row), staged via global_load_lds (16 B/lane).
// Fragments per 16x16x32 MFMA: A row=lane&15, k=(lane>>4)*8+j ; same for W rows.
template<int BM, int BN>
__device__ inline void mm_core(const bf16* A, int lda, const bf16* W, int ldw, int K,
                               char* As, char* Bs, f32x4 (&acc)[BM/32][BN/32]) {
    constexpr int MR = BM/32, NR = BN/32;
    constexpr int AC = (BM*64)/4096;   // staging issues for A tile
    constexpr int BC = (BN*64)/4096;
    const int tid  = threadIdx.x;
    const int lane = tid & 63;
    const int wv   = tid >> 6;
    const int wr   = wv >> 1, wc = wv & 1;

    for (int k0 = 0; k0 < K; k0 += 32) {
#pragma unroll
        for (int i = 0; i < AC; i++) {
            int c = i*256 + tid;
            const char* g = (const char*)A + ((size_t)(c>>2) * lda + k0) * 2 + (c&3)*16;
            char* l = As + (size_t)(c & ~63) * 16;
            gload_lds16(g, l);
        }
#pragma unroll
        for (int i = 0; i < BC; i++) {
            int c = i*256 + tid;
            const char* g = (const char*)W + ((size_t)(c>>2) * ldw + k0) * 2 + (c&3)*16;
            char* l = Bs + (size_t)(c & ~63) * 16;
            gload_lds16(g, l);
        }
        __syncthreads();
        short8 af[MR], bfv[NR];
        int ko = (lane >> 4) * 16;
#pragma unroll
        for (int m = 0; m < MR; m++)
            af[m] = *(const short8*)(As + (wr*(BM/2) + m*16 + (lane&15)) * 64 + ko);
#pragma unroll
        for (int n = 0; n < NR; n++)
            bfv[n] = *(const short8*)(Bs + (wc*(BN/2) + n*16 + (lane&15)) * 64 + ko);
#pragma unroll
        for (int m = 0; m < MR; m++)
#pragma unroll
            for (int n = 0; n < NR; n++)
                acc[m][n] = __builtin_amdgcn_mfma_f32_16x16x32_bf16(af[m], bfv[n], acc[m][n], 0, 0, 0);
        __syncthreads();
    }
}

// Layer GEMM. EPI: 0 = bf16 out + bias ; 1 = bf16 out + bias + relu ; 2 = f32 out + bias
template<int BM, int BN, int EPI>
__global__ __launch_bounds__(256) void k_mm(const bf16* __restrict__ A, int lda,
                                            const bf16* __restrict__ W, int ldw,
                                            const float* __restrict__ bias,
                                            bf16* __restrict__ Cb, float* __restrict__ Cf,
                                            int ldc, int K) {
    __shared__ char smem[(BM+BN)*64];
    const int bm = blockIdx.y * BM, bn = blockIdx.x * BN;
    f32x4 acc[BM/32][BN/32] = {};
    mm_core<BM,BN>(A + (size_t)bm * lda, lda, W + (size_t)bn * ldw, ldw, K,
                   smem, smem + BM*64, acc);
    const int lane = threadIdx.x & 63;
    const int wv = threadIdx.x >> 6, wr = wv>>1, wc = wv&1;
#pragma unroll
    for (int m = 0; m < BM/32; m++)
#pragma unroll
        for (int n = 0; n < BN/32; n++)
#pragma unroll
            for (int j = 0; j < 4; j++) {
                int row = bm + wr*(BM/2) + m*16 + (lane>>4)*4 + j;
                int col = bn + wc*(BN/2) + n*16 + (lane&15);
                float v = acc[m][n][j] + bias[col];
                if (EPI == 1) v = fmaxf(v, 0.0f);
                if (EPI == 2) Cf[(size_t)row*ldc + col] = v;
                else          Cb[(size_t)row*ldc + col] = __float2bfloat16(v);
            }
}

// Batched scores: z=(b,h); sc = Q@K^T*scale + bias, bf16 out. M=N=512, K=64.
template<int BM, int BN>
__global__ __launch_bounds__(256) void k_mm_scores(const bf16* __restrict__ qkv,
                                                   const bf16* __restrict__ bias,
                                                   bf16* __restrict__ sc) {
    __shared__ char smem[(BM+BN)*64];
    const int z = blockIdx.z;
    const int b = z >> 3, h = z & 7;
    const int bm = blockIdx.y * BM, bn = blockIdx.x * BN;
    const bf16* A = qkv + (size_t)b*CS*(3*CD) + h*CDH;            // Q rows
    const bf16* W = qkv + (size_t)b*CS*(3*CD) + CD + h*CDH;       // K rows
    f32x4 acc[BM/32][BN/32] = {};
    mm_core<BM,BN>(A + (size_t)bm*(3*CD), 3*CD, W + (size_t)bn*(3*CD), 3*CD, CDH,
                   smem, smem + BM*64, acc);
    const bf16* bmat = bias + (size_t)z*CS*CS;
    bf16* out = sc + (size_t)z*CS*CS;
    const int lane = threadIdx.x & 63;
    const int wv = threadIdx.x >> 6, wr = wv>>1, wc = wv&1;
#pragma unroll
    for (int m = 0; m < BM/32; m++)
#pragma unroll
        for (int n = 0; n < BN/32; n++)
#pragma unroll
            for (int j = 0; j < 4; j++) {
                int row = bm + wr*(BM/2) + m*16 + (lane>>4)*4 + j;
                int col = bn + wc*(BN/2) + n*16 + (lane&15);
                float v = acc[m][n][j] * 0.125f + __bfloat162float(bmat[(size_t)row*CS + col]);
                out[(size_t)row*CS + col] = __float2bfloat16(v);
            }
}

// Batched PV: z=(b,h); att_part = P @ Vt^T. M=512, N=64, K=512. No bias.
template<int BM, int BN>
__global__ __launch_bounds__(256) void k_mm_pv(const bf16* __restrict__ P,
                                               const bf16* __restrict__ vt,
                                               bf16* __restrict__ att) {
    __shared__ char smem[(BM+BN)*64];
    const int z = blockIdx.z;
    const int b = z >> 3, h = z & 7;
    const int bm = blockIdx.y * BM, bn = blockIdx.x * BN;
    f32x4 acc[BM/32][BN/32] = {};
    mm_core<BM,BN>(P + (size_t)z*CS*CS + (size_t)bm*CS, CS,
                   vt + (size_t)z*CDH*CS + (size_t)bn*CS, CS, CS,
                   smem, smem + BM*64, acc);
    bf16* out = att + (size_t)b*CS*CD + h*CDH;
    const int lane = threadIdx.x & 63;
    const int wv = threadIdx.x >> 6, wr = wv>>1, wc = wv&1;
#pragma unroll
    for (int m = 0; m < BM/32; m++)
#pragma unroll
        for (int n = 0; n < BN/32; n++)
#pragma unroll
            for (int j = 0; j < 4; j++) {
                int row = bm + wr*(BM/2) + m*16 + (lane>>4)*4 + j;
                int col = bn + wc*(BN/2) + n*16 + (lane&15);
                out[(size_t)row*CD + col] = __float2bfloat16(acc[m][n][j]);
            }
}

// row softmax in place on bf16 scores; one wave per row of 512
__global__ __launch_bounds__(256) void k_softmax(bf16* __restrict__ sc) {
    int row  = blockIdx.x * 4 + (threadIdx.x >> 6);
    int lane = threadIdx.x & 63;
    bf16* p = sc + (size_t)row * CS + lane * 8;
    short8 raw = *(const short8*)p;
    float v[8];
#pragma unroll
    for (int j = 0; j < 8; j++)
        v[j] = __uint_as_float(((uint32_t)(uint16_t)raw[j]) << 16);
    float m = v[0];
#pragma unroll
    for (int j = 1; j < 8; j++) m = fmaxf(m, v[j]);
    for (int o = 32; o > 0; o >>= 1) m = fmaxf(m, __shfl_xor(m, o));
    float s = 0.f;
#pragma unroll
    for (int j = 0; j < 8; j++) { v[j] = expf(v[j] - m); s += v[j]; }
    for (int o = 32; o > 0; o >>= 1) s += __shfl_xor(s, o);
    float inv = 1.0f / s;
    short8 ov;
#pragma unroll
    for (int j = 0; j < 8; j++) ov[j] = __builtin_bit_cast(short, __float2bfloat16(v[j] * inv));
    *(short8*)p = ov;
}

// transpose V slice: vt[(b,h)][d][s] = qkv_v[(b,s)][h][d]
__global__ __launch_bounds__(256) void k_vt(const bf16* __restrict__ qkv, bf16* __restrict__ vt) {
    __shared__ unsigned short tile[64][65];
    const int bh = blockIdx.y, b = bh >> 3, h = bh & 7;
    const int s0 = blockIdx.x * 64;
    const int t = threadIdx.x, r = t >> 2, quad = t & 3;
    const bf16* src = qkv + ((size_t)(b*CS + s0 + r))*(3*CD) + 2*CD + h*CDH + quad*16;
    short8 v0 = *(const short8*)src;
    short8 v1 = *(const short8*)(src + 8);
#pragma unroll
    for (int j = 0; j < 8; j++) {
        tile[r][quad*16 + j]     = (unsigned short)v0[j];
        tile[r][quad*16 + 8 + j] = (unsigned short)v1[j];
    }
    __syncthreads();
    bf16* out = vt + ((size_t)bh*CDH + r)*CS + s0 + quad*16;
    short8 o0, o1;
#pragma unroll
    for (int j = 0; j < 8; j++) {
        o0[j] = (short)tile[quad*16 + j][r];
        o1[j] = (short)tile[quad*16 + 8 + j][r];
    }
    *(short8*)out = o0;
    *(short8*)(out + 8) = o1;
}

// ---------------------------------------------------------------------------
__global__ void k_standardize(const float* __restrict__ x, float* __restrict__ ts,
                              float* __restrict__ fs) {
    int b = blockIdx.x, ch = blockIdx.y, tid = threadIdx.x;
    __shared__ float red[256];
    float v0 = x[(b*CS + tid)*CF + ch];
    float v1 = x[(b*CS + tid + 256)*CF + ch];
    red[tid] = v0 + v1; __syncthreads();
    for (int w = 128; w > 0; w >>= 1) { if (tid < w) red[tid] += red[tid+w]; __syncthreads(); }
    float mean = red[0] * (1.0f/CS); __syncthreads();
    float d0 = v0-mean, d1 = v1-mean;
    red[tid] = d0*d0 + d1*d1; __syncthreads();
    for (int w = 128; w > 0; w >>= 1) { if (tid < w) red[tid] += red[tid+w]; __syncthreads(); }
    float inv = rsqrtf(red[0]*(1.0f/CS) + 1e-6f);
    float* o = ch == 0 ? ts : fs;
    o[b*CS + tid] = d0*inv; o[b*CS + tid + 256] = d1*inv;
}

__global__ __launch_bounds__(256) void k_relpos(const float* __restrict__ ts, const float* __restrict__ fs,
                         const float* __restrict__ w1, const float* __restrict__ b1,
                         const float* __restrict__ w2, const float* __restrict__ b2,
                         bf16* __restrict__ bias) {
    int idx = blockIdx.x * 256 + threadIdx.x;
    int j = idx & (CS-1), i = (idx >> 9) & (CS-1), b = idx >> 18;
    float dt = ts[b*CS + i] - ts[b*CS + j];
    float df = fs[b*CS + i] - fs[b*CS + j];
    float acc[CH];
#pragma unroll
    for (int h = 0; h < CH; h++) acc[h] = b2[h];
    for (int r = 0; r < CRPH; r++) {
        float hd = fmaxf(w1[r*2]*dt + w1[r*2+1]*df + b1[r], 0.0f);
#pragma unroll
        for (int h = 0; h < CH; h++) acc[h] += w2[h*CRPH + r] * hd;
    }
#pragma unroll
    for (int h = 0; h < CH; h++) {
        float v = fminf(fmaxf(acc[h], -5.0f), 5.0f);
        bias[((size_t)(b*CH + h)*CS + i)*CS + j] = __float2bfloat16(v);
    }
}

__global__ __launch_bounds__(256) void k_embed(const float* __restrict__ x, const float* __restrict__ w,
                        const float* __restrict__ bv, float* __restrict__ h, bf16* __restrict__ hb) {
    int idx = blockIdx.x * 256 + threadIdx.x;
    int d = idx & (CD-1), m = idx >> 9;
    const float* xr = x + m*CF;
    const float* wr = w + d*CF;
    float acc = bv[d];
#pragma unroll
    for (int f = 0; f < CF; f++) acc += xr[f]*wr[f];
    h[idx] = acc; hb[idx] = __float2bfloat16(acc);
}

__global__ __launch_bounds__(256) void k_ln(float* __restrict__ h, const float* __restrict__ add,
                     const float* __restrict__ s, const float* __restrict__ bv, bf16* __restrict__ hb) {
    int row = blockIdx.x, tid = threadIdx.x;
    __shared__ float red[256];
    float v0 = h[(size_t)row*CD + tid]       + add[(size_t)row*CD + tid];
    float v1 = h[(size_t)row*CD + tid + 256] + add[(size_t)row*CD + tid + 256];
    red[tid] = v0 + v1; __syncthreads();
    for (int w = 128; w > 0; w >>= 1) { if (tid < w) red[tid] += red[tid+w]; __syncthreads(); }
    float mean = red[0] * (1.0f/CD); __syncthreads();
    float d0 = v0-mean, d1 = v1-mean;
    red[tid] = d0*d0 + d1*d1; __syncthreads();
    for (int w = 128; w > 0; w >>= 1) { if (tid < w) red[tid] += red[tid+w]; __syncthreads(); }
    float inv = rsqrtf(red[0]*(1.0f/CD) + 1e-5f);
    float o0 = d0*inv*s[tid] + bv[tid];
    float o1 = d1*inv*s[tid+256] + bv[tid+256];
    h[(size_t)row*CD + tid] = o0;       hb[(size_t)row*CD + tid] = __float2bfloat16(o0);
    h[(size_t)row*CD + tid + 256] = o1; hb[(size_t)row*CD + tid + 256] = __float2bfloat16(o1);
}

// convert one layer's 4 weight blocks to bf16 (layout: aiw|aow|f1w|f2w)
__global__ __launch_bounds__(256) void k_wconv(const float* __restrict__ a0, const float* __restrict__ a1,
                        const float* __restrict__ a2, const float* __restrict__ a3,
                        bf16* __restrict__ dst) {
    size_t i = ((size_t)blockIdx.x * 256 + threadIdx.x) * 8;
    const float* src; size_t off;
    if (i < 786432)       { src = a0; off = i; }
    else if (i < 1048576) { src = a1; off = i - 786432; }
    else if (i < 2097152) { src = a2; off = i - 1048576; }
    else                  { src = a3; off = i - 2097152; }
    short8 o;
#pragma unroll
    for (int j = 0; j < 8; j++) o[j] = __builtin_bit_cast(short, __float2bfloat16(src[off + j]));
    *(short8*)(void*)(dst + i) = o;
}

__global__ void k_poolfc(const float* __restrict__ h, const float* __restrict__ fcw,
                         const float* __restrict__ fcb, float* __restrict__ out) {
    int b = blockIdx.x, tid = threadIdx.x;
    __shared__ float rep[CD];
    for (int d = tid; d < CD; d += 256) {
        float acc = 0.0f;
        for (int s0 = 0; s0 < CS; s0++) acc += h[((size_t)(b*CS + s0))*CD + d];
        rep[d] = acc * (1.0f/CS);
    }
    __syncthreads();
    if (tid < CNC) {
        float acc = fcb[tid];
        for (int d = 0; d < CD; d++) acc += rep[d]*fcw[tid*CD + d];
        out[b*CNC + tid] = acc;
    }
}

// ---------------------------------------------------------------------------
extern "C" void kernel_launch(void* const* d_in, const int* in_sizes, int n_in,
                              void* d_out, int out_size, void* d_ws, size_t ws_size,
                              hipStream_t stream) {
    const float* x   = (const float*)d_in[0];
    const float* rw1 = (const float*)d_in[1];
    const float* rb1 = (const float*)d_in[2];
    const float* rw2 = (const float*)d_in[3];
    const float* rb2 = (const float*)d_in[4];
    const float* emw = (const float*)d_in[5];
    const float* emb = (const float*)d_in[6];
    const float* aiw = (const float*)d_in[7];
    const float* aib = (const float*)d_in[8];
    const float* aow = (const float*)d_in[9];
    const float* aob = (const float*)d_in[10];
    const float* f1w = (const float*)d_in[11];
    const float* f1b = (const float*)d_in[12];
    const float* f2w = (const float*)d_in[13];
    const float* f2b = (const float*)d_in[14];
    const float* l1s = (const float*)d_in[15];
    const float* l1b = (const float*)d_in[16];
    const float* l2s = (const float*)d_in[17];
    const float* l2b = (const float*)d_in[18];
    const float* fcw = (const float*)d_in[19];
    const float* fcb = (const float*)d_in[20];
    float* out = (float*)d_out;

    char* p = (char*)d_ws;
    auto alloc = [&](size_t bytes) { char* r = p; p += (bytes + 255) & ~(size_t)255; return r; };
    bf16*  biasb = (bf16*)alloc((size_t)CB*CH*CS*CS*2);    // 16.78 MB
    float* h     = (float*)alloc((size_t)CB*CS*CD*4);      // 4.19 MB
    bf16*  hb    = (bf16*)alloc((size_t)CB*CS*CD*2);       // 2.10 MB
    bf16*  qkvb  = (bf16*)alloc((size_t)CB*CS*3*CD*2);     // 6.29 MB
    bf16*  scb   = (bf16*)alloc((size_t)CB*CH*CS*CS*2);    // 16.78 MB
    bf16*  vtb   = (bf16*)alloc((size_t)CB*CH*CDH*CS*2);   // 2.10 MB
    bf16*  attb  = (bf16*)alloc((size_t)CB*CS*CD*2);       // 2.10 MB
    float* tmp   = (float*)alloc((size_t)CB*CS*CD*4);      // 4.19 MB
    bf16*  ffb   = (bf16*)alloc((size_t)CB*CS*CDFF*2);     // 8.39 MB
    bf16*  wl    = (bf16*)alloc((size_t)3145728*2);        // 6.29 MB
    float* ts    = (float*)alloc(CB*CS*4);
    float* fs    = (float*)alloc(CB*CS*4);

    const int M = CB*CS;  // 2048

    k_standardize<<<dim3(CB,2), 256, 0, stream>>>(x, ts, fs);
    k_relpos<<<(CB*CS*CS)/256, 256, 0, stream>>>(ts, fs, rw1, rb1, rw2, rb2, biasb);
    k_embed<<<(M*CD)/256, 256, 0, stream>>>(x, emw, emb, h, hb);

    for (int l = 0; l < CL; l++) {
        const bf16* wl_aiw = wl;
        const bf16* wl_aow = wl + 786432;
        const bf16* wl_f1w = wl + 1048576;
        const bf16* wl_f2w = wl + 2097152;
        k_wconv<<<1536, 256, 0, stream>>>(aiw + (size_t)l*786432, aow + (size_t)l*262144,
                                          f1w + (size_t)l*1048576, f2w + (size_t)l*1048576, wl);
        // qkv = h @ aiw^T + aib   (bf16 out)
        k_mm<128,128,0><<<dim3(12,16), 256, 0, stream>>>(hb, CD, wl_aiw, CD,
                                                         aib + (size_t)l*3*CD, qkvb, nullptr, 3*CD, CD);
        // scores + bias (bf16), softmax in place, V transpose, PV
        k_mm_scores<128,128><<<dim3(4,4,CB*CH), 256, 0, stream>>>(qkvb, biasb, scb);
        k_softmax<<<(CB*CH*CS)/4, 256, 0, stream>>>(scb);
        k_vt<<<dim3(CS/64, CB*CH), 256, 0, stream>>>(qkvb, vtb);
        k_mm_pv<64,64><<<dim3(1,8,CB*CH), 256, 0, stream>>>(scb, vtb, attb);
        // out projection -> tmp (f32)
        k_mm<64,64,2><<<dim3(8,32), 256, 0, stream>>>(attb, CD, wl_aow, CD,
                                                      aob + (size_t)l*CD, nullptr, tmp, CD, CD);
        k_ln<<<M, 256, 0, stream>>>(h, tmp, l1s + (size_t)l*CD, l1b + (size_t)l*CD, hb);
        // ff1 (relu, bf16 out)
        k_mm<128,128,1><<<dim3(16,16), 256, 0, stream>>>(hb, CD, wl_f1w, CD,
                                                         f1b + (size_t)l*CDFF, ffb, nullptr, CDFF, CD);
        // ff2 -> tmp (f32)
        k_mm<64,64,2><<<dim3(8,32), 256, 0, stream>>>(ffb, CDFF, wl_f2w, CDFF,
                                                      f2b + (size_t)l*CD, nullptr, tmp, CD, CDFF);
        k_ln<<<M, 256, 0, stream>>>(h, tmp, l2s + (size_t)l*CD, l2b + (size_t)l*CD, hb);
    }

    k_poolfc<<<CB, 256, 0, stream>>>(h, fcw, fcb, out);
}

// Round 3
// 676.589 us; speedup vs baseline: 9.1766x; 1.0940x over previous
//
#include <hip/hip_runtime.h>
#include <hip/hip_bf16.h>
#include <stdint.h>

using short8 = __attribute__((ext_vector_type(8))) short;
using us4    = __attribute__((ext_vector_type(4))) unsigned short;
using f32x4  = __attribute__((ext_vector_type(4))) float;
using bf16   = __hip_bfloat16;

constexpr int CB=4, CS=512, CF=16, CD=512, CH=8, CL=6, CDFF=2048, CNC=12, CRPH=64, CDH=64;

__device__ inline void gload_lds16(const void* g, void* l) {
    __builtin_amdgcn_global_load_lds((const __attribute__((address_space(1))) void*)g,
                                     (__attribute__((address_space(3))) void*)l, 16, 0, 0);
}
__device__ inline float bfbits2f(unsigned short u) {
    return __uint_as_float(((uint32_t)u) << 16);
}
__device__ inline unsigned short f2bfbits(float f) {
    return __builtin_bit_cast(unsigned short, __float2bfloat16(f));
}

// ---------------------------------------------------------------------------
// MFMA GEMM core (m97 structure): C[BM][BN] += A[BM][K] * W[BN][K]^T
template<int BM, int BN>
__device__ inline void mm_core(const bf16* A, int lda, const bf16* W, int ldw, int K,
                               char* As, char* Bs, f32x4 (&acc)[BM/32][BN/32]) {
    constexpr int MR = BM/32, NR = BN/32;
    constexpr int AC = (BM*64)/4096;
    constexpr int BC = (BN*64)/4096;
    const int tid  = threadIdx.x;
    const int lane = tid & 63;
    const int wv   = tid >> 6;
    const int wr   = wv >> 1, wc = wv & 1;

    for (int k0 = 0; k0 < K; k0 += 32) {
#pragma unroll
        for (int i = 0; i < AC; i++) {
            int c = i*256 + tid;
            const char* g = (const char*)A + ((size_t)(c>>2) * lda + k0) * 2 + (c&3)*16;
            gload_lds16(g, As + (size_t)(c & ~63) * 16);
        }
#pragma unroll
        for (int i = 0; i < BC; i++) {
            int c = i*256 + tid;
            const char* g = (const char*)W + ((size_t)(c>>2) * ldw + k0) * 2 + (c&3)*16;
            gload_lds16(g, Bs + (size_t)(c & ~63) * 16);
        }
        __syncthreads();
        short8 af[MR], bfv[NR];
        int ko = (lane >> 4) * 16;
#pragma unroll
        for (int m = 0; m < MR; m++)
            af[m] = *(const short8*)(As + (wr*(BM/2) + m*16 + (lane&15)) * 64 + ko);
#pragma unroll
        for (int n = 0; n < NR; n++)
            bfv[n] = *(const short8*)(Bs + (wc*(BN/2) + n*16 + (lane&15)) * 64 + ko);
#pragma unroll
        for (int m = 0; m < MR; m++)
#pragma unroll
            for (int n = 0; n < NR; n++)
                acc[m][n] = __builtin_amdgcn_mfma_f32_16x16x32_bf16(af[m], bfv[n], acc[m][n], 0, 0, 0);
        __syncthreads();
    }
}

// EPI: 0 = bf16 out + bias ; 1 = bf16 out + bias + relu ; 2 = f32 out + bias
template<int BM, int BN, int EPI>
__global__ __launch_bounds__(256) void k_mm(const bf16* __restrict__ A, int lda,
                                            const bf16* __restrict__ W, int ldw,
                                            const float* __restrict__ bias,
                                            bf16* __restrict__ Cb, float* __restrict__ Cf,
                                            int ldc, int K) {
    __shared__ char smem[(BM+BN)*64];
    const int bm = blockIdx.y * BM, bn = blockIdx.x * BN;
    f32x4 acc[BM/32][BN/32] = {};
    mm_core<BM,BN>(A + (size_t)bm * lda, lda, W + (size_t)bn * ldw, ldw, K,
                   smem, smem + BM*64, acc);
    const int lane = threadIdx.x & 63;
    const int wv = threadIdx.x >> 6, wr = wv>>1, wc = wv&1;
#pragma unroll
    for (int m = 0; m < BM/32; m++)
#pragma unroll
        for (int n = 0; n < BN/32; n++)
#pragma unroll
            for (int j = 0; j < 4; j++) {
                int row = bm + wr*(BM/2) + m*16 + (lane>>4)*4 + j;
                int col = bn + wc*(BN/2) + n*16 + (lane&15);
                float v = acc[m][n][j] + bias[col];
                if (EPI == 1) v = fmaxf(v, 0.0f);
                if (EPI == 2) Cf[(size_t)row*ldc + col] = v;
                else          Cb[(size_t)row*ldc + col] = __float2bfloat16(v);
            }
}

// ---------------------------------------------------------------------------
// Fused attention: per (b,h) and 64-row Q tile: S^T = K@Q^T (+bias, scale),
// online softmax (q lane-local), P -> LDS (XOR-swizzled), O^T = Vt@P^T.
__global__ __launch_bounds__(256) void k_attn_fused(const bf16* __restrict__ qkv,
                                                    const bf16* __restrict__ vt,
                                                    const bf16* __restrict__ bias,
                                                    bf16* __restrict__ att) {
    __shared__ char Ks[16384];   // K tile  [128 kv][64 dh]   rows 128 B, src pre-swizzled
    __shared__ char Vs[16384];   // Vt tile [64 d][128 kv]    rows 256 B, src pre-swizzled
    __shared__ char Ps[16384];   // P per wave [16 q][128 kv] rows 256 B, swizzled writes

    const int z = blockIdx.y, b = z >> 3, h = z & 7;
    const int qbase = blockIdx.x * 64;
    const int tid = threadIdx.x, l = tid & 63, w = tid >> 6;
    const int g = l >> 4, c = l & 15, swz = l & 7;
    const int q_global = qbase + w*16 + c;

    // Q fragments for this wave's 16-q stripe (held in registers for all KV tiles)
    const bf16* qrow = qkv + ((size_t)(b*CS + q_global))*(3*CD) + h*CDH;
    short8 bq0 = *(const short8*)(qrow + g*8);
    short8 bq1 = *(const short8*)(qrow + 32 + g*8);
    const bf16* brow = bias + ((size_t)z*CS + q_global)*CS;

    float mrun = -1e30f, lsum = 0.0f;
    f32x4 accO[4] = {};
    char* Pb = Ps + w*4096;

    for (int kv0 = 0; kv0 < CS; kv0 += 128) {
        // stage K tile (1024 16B slots) — source col-unit pre-swizzled by row
#pragma unroll
        for (int i = 0; i < 4; i++) {
            int s = i*256 + tid;
            int r = s >> 3, u = s & 7;
            const bf16* gk = qkv + ((size_t)(b*CS + kv0 + r))*(3*CD) + CD + h*CDH + ((u ^ (r&7)) * 8);
            gload_lds16(gk, Ks + (size_t)(s & ~63)*16);
        }
        // stage Vt tile
#pragma unroll
        for (int i = 0; i < 4; i++) {
            int s = i*256 + tid;
            int d = s >> 4, u = s & 15;
            const bf16* gv = vt + ((size_t)(z*CDH + d))*CS + kv0 + ((u ^ (d&7)) * 8);
            gload_lds16(gv, Vs + (size_t)(s & ~63)*16);
        }
        __syncthreads();

        // S^T[kcol][q] = sum_dh K[kcol][dh] * Q[q][dh]
        float sv[8][4];
        float tmax = -1e30f;
#pragma unroll
        for (int n = 0; n < 8; n++) {
            int row = n*16 + c;
            short8 af0 = *(const short8*)(Ks + row*128 + ((g    ^ swz) * 16));
            short8 af1 = *(const short8*)(Ks + row*128 + (((4+g) ^ swz) * 16));
            f32x4 a = {};
            a = __builtin_amdgcn_mfma_f32_16x16x32_bf16(af0, bq0, a, 0, 0, 0);
            a = __builtin_amdgcn_mfma_f32_16x16x32_bf16(af1, bq1, a, 0, 0, 0);
            us4 b4 = *(const us4*)(brow + kv0 + n*16 + g*4);
#pragma unroll
            for (int j = 0; j < 4; j++) {
                sv[n][j] = a[j] * 0.125f + bfbits2f(b4[j]);
                tmax = fmaxf(tmax, sv[n][j]);
            }
        }
        tmax = fmaxf(tmax, __shfl_xor(tmax, 16));
        tmax = fmaxf(tmax, __shfl_xor(tmax, 32));
        float mnew = fmaxf(mrun, tmax);
        float corr = __expf(mrun - mnew);
        float tsum = 0.0f;
#pragma unroll
        for (int n = 0; n < 8; n++)
#pragma unroll
            for (int j = 0; j < 4; j++) {
                float e = __expf(sv[n][j] - mnew);
                sv[n][j] = e;
                tsum += e;
            }
        tsum += __shfl_xor(tsum, 16);
        tsum += __shfl_xor(tsum, 32);
        lsum = lsum * corr + tsum;
        mrun = mnew;
#pragma unroll
        for (int n2 = 0; n2 < 4; n2++)
#pragma unroll
            for (int j = 0; j < 4; j++) accO[n2][j] *= corr;

        // P[q][kcol] -> LDS, 8B packed writes, XOR-swizzled
#pragma unroll
        for (int n = 0; n < 8; n++) {
            us4 pk;
#pragma unroll
            for (int j = 0; j < 4; j++) pk[j] = f2bfbits(sv[n][j]);
            *(us4*)(Pb + c*256 + ((n*32 + g*8) ^ (swz << 4))) = pk;
        }

        // O^T[d][q] += sum_k Vt[d][k] * P[q][k]
#pragma unroll
        for (int n2 = 0; n2 < 4; n2++) {
            int d = n2*16 + c;
#pragma unroll
            for (int kk = 0; kk < 4; kk++) {
                short8 av = *(const short8*)(Vs + d*256 + (((kk*4 + g) ^ swz) * 16));
                short8 bp = *(const short8*)(Pb + c*256 + (((kk*64 + g*16) ^ (swz << 4))));
                accO[n2] = __builtin_amdgcn_mfma_f32_16x16x32_bf16(av, bp, accO[n2], 0, 0, 0);
            }
        }
        __syncthreads();
    }

    float inv = 1.0f / lsum;
    bf16* orow = att + ((size_t)(b*CS + q_global))*CD + h*CDH;
#pragma unroll
    for (int n2 = 0; n2 < 4; n2++) {
        us4 o;
#pragma unroll
        for (int j = 0; j < 4; j++) o[j] = f2bfbits(accO[n2][j] * inv);
        *(us4*)(orow + n2*16 + g*4) = o;
    }
}

// transpose V slice: vt[(b,h)][d][s] = qkv_v[(b,s)][h][d]
__global__ __launch_bounds__(256) void k_vt(const bf16* __restrict__ qkv, bf16* __restrict__ vt) {
    __shared__ unsigned short tile[64][65];
    const int bh = blockIdx.y, b = bh >> 3, h = bh & 7;
    const int s0 = blockIdx.x * 64;
    const int t = threadIdx.x, r = t >> 2, quad = t & 3;
    const bf16* src = qkv + ((size_t)(b*CS + s0 + r))*(3*CD) + 2*CD + h*CDH + quad*16;
    short8 v0 = *(const short8*)src;
    short8 v1 = *(const short8*)(src + 8);
#pragma unroll
    for (int j = 0; j < 8; j++) {
        tile[r][quad*16 + j]     = (unsigned short)v0[j];
        tile[r][quad*16 + 8 + j] = (unsigned short)v1[j];
    }
    __syncthreads();
    bf16* out = vt + ((size_t)bh*CDH + r)*CS + s0 + quad*16;
    short8 o0, o1;
#pragma unroll
    for (int j = 0; j < 8; j++) {
        o0[j] = (short)tile[quad*16 + j][r];
        o1[j] = (short)tile[quad*16 + 8 + j][r];
    }
    *(short8*)out = o0;
    *(short8*)(out + 8) = o1;
}

// ---------------------------------------------------------------------------
__global__ void k_standardize(const float* __restrict__ x, float* __restrict__ ts,
                              float* __restrict__ fs) {
    int b = blockIdx.x, ch = blockIdx.y, tid = threadIdx.x;
    __shared__ float red[256];
    float v0 = x[(b*CS + tid)*CF + ch];
    float v1 = x[(b*CS + tid + 256)*CF + ch];
    red[tid] = v0 + v1; __syncthreads();
    for (int w = 128; w > 0; w >>= 1) { if (tid < w) red[tid] += red[tid+w]; __syncthreads(); }
    float mean = red[0] * (1.0f/CS); __syncthreads();
    float d0 = v0-mean, d1 = v1-mean;
    red[tid] = d0*d0 + d1*d1; __syncthreads();
    for (int w = 128; w > 0; w >>= 1) { if (tid < w) red[tid] += red[tid+w]; __syncthreads(); }
    float inv = rsqrtf(red[0]*(1.0f/CS) + 1e-6f);
    float* o = ch == 0 ? ts : fs;
    o[b*CS + tid] = d0*inv; o[b*CS + tid + 256] = d1*inv;
}

__global__ __launch_bounds__(256) void k_relpos(const float* __restrict__ ts, const float* __restrict__ fs,
                         const float* __restrict__ w1, const float* __restrict__ b1,
                         const float* __restrict__ w2, const float* __restrict__ b2,
                         bf16* __restrict__ bias) {
    int idx = blockIdx.x * 256 + threadIdx.x;
    int j = idx & (CS-1), i = (idx >> 9) & (CS-1), b = idx >> 18;
    float dt = ts[b*CS + i] - ts[b*CS + j];
    float df = fs[b*CS + i] - fs[b*CS + j];
    float acc[CH];
#pragma unroll
    for (int h = 0; h < CH; h++) acc[h] = b2[h];
    for (int r = 0; r < CRPH; r++) {
        float hd = fmaxf(w1[r*2]*dt + w1[r*2+1]*df + b1[r], 0.0f);
#pragma unroll
        for (int h = 0; h < CH; h++) acc[h] += w2[h*CRPH + r] * hd;
    }
#pragma unroll
    for (int h = 0; h < CH; h++) {
        float v = fminf(fmaxf(acc[h], -5.0f), 5.0f);
        bias[((size_t)(b*CH + h)*CS + i)*CS + j] = __float2bfloat16(v);
    }
}

__global__ __launch_bounds__(256) void k_embed(const float* __restrict__ x, const float* __restrict__ w,
                        const float* __restrict__ bv, float* __restrict__ h, bf16* __restrict__ hb) {
    int idx = blockIdx.x * 256 + threadIdx.x;
    int d = idx & (CD-1), m = idx >> 9;
    const float* xr = x + m*CF;
    const float* wr = w + d*CF;
    float acc = bv[d];
#pragma unroll
    for (int f = 0; f < CF; f++) acc += xr[f]*wr[f];
    h[idx] = acc; hb[idx] = __float2bfloat16(acc);
}

__global__ __launch_bounds__(256) void k_ln(float* __restrict__ h, const float* __restrict__ add,
                     const float* __restrict__ s, const float* __restrict__ bv, bf16* __restrict__ hb) {
    int row = blockIdx.x, tid = threadIdx.x;
    __shared__ float red[256];
    float v0 = h[(size_t)row*CD + tid]       + add[(size_t)row*CD + tid];
    float v1 = h[(size_t)row*CD + tid + 256] + add[(size_t)row*CD + tid + 256];
    red[tid] = v0 + v1; __syncthreads();
    for (int w = 128; w > 0; w >>= 1) { if (tid < w) red[tid] += red[tid+w]; __syncthreads(); }
    float mean = red[0] * (1.0f/CD); __syncthreads();
    float d0 = v0-mean, d1 = v1-mean;
    red[tid] = d0*d0 + d1*d1; __syncthreads();
    for (int w = 128; w > 0; w >>= 1) { if (tid < w) red[tid] += red[tid+w]; __syncthreads(); }
    float inv = rsqrtf(red[0]*(1.0f/CD) + 1e-5f);
    float o0 = d0*inv*s[tid] + bv[tid];
    float o1 = d1*inv*s[tid+256] + bv[tid+256];
    h[(size_t)row*CD + tid] = o0;       hb[(size_t)row*CD + tid] = __float2bfloat16(o0);
    h[(size_t)row*CD + tid + 256] = o1; hb[(size_t)row*CD + tid + 256] = __float2bfloat16(o1);
}

__global__ __launch_bounds__(256) void k_wconv(const float* __restrict__ a0, const float* __restrict__ a1,
                        const float* __restrict__ a2, const float* __restrict__ a3,
                        bf16* __restrict__ dst) {
    size_t i = ((size_t)blockIdx.x * 256 + threadIdx.x) * 8;
    const float* src; size_t off;
    if (i < 786432)       { src = a0; off = i; }
    else if (i < 1048576) { src = a1; off = i - 786432; }
    else if (i < 2097152) { src = a2; off = i - 1048576; }
    else                  { src = a3; off = i - 2097152; }
    short8 o;
#pragma unroll
    for (int j = 0; j < 8; j++) o[j] = __builtin_bit_cast(short, __float2bfloat16(src[off + j]));
    *(short8*)(void*)(dst + i) = o;
}

// pool: rep[b][d] = mean over s of h[b][s][d]; grid (B, D/64), 256 threads
__global__ __launch_bounds__(256) void k_pool(const float* __restrict__ h, float* __restrict__ rep) {
    int b = blockIdx.x, d0 = blockIdx.y * 64;
    int t = threadIdx.x, dl = t & 63, sg = t >> 6;
    float acc = 0.0f;
    for (int s = sg*128; s < sg*128 + 128; s++)
        acc += h[((size_t)(b*CS + s))*CD + d0 + dl];
    __shared__ float red[256];
    red[t] = acc; __syncthreads();
    if (t < 64)
        rep[b*CD + d0 + dl] = (red[t] + red[t+64] + red[t+128] + red[t+192]) * (1.0f/CS);
}

// fc: out[b][c] = rep[b] . fcw[c] + fcb[c]; grid (B, NC), 64 threads
__global__ void k_fc(const float* __restrict__ rep, const float* __restrict__ fcw,
                     const float* __restrict__ fcb, float* __restrict__ out) {
    int b = blockIdx.x, cc = blockIdx.y, l = threadIdx.x;
    float acc = 0.0f;
    for (int d = l; d < CD; d += 64) acc += rep[b*CD + d] * fcw[cc*CD + d];
    for (int o = 32; o > 0; o >>= 1) acc += __shfl_xor(acc, o);
    if (l == 0) out[b*CNC + cc] = acc + fcb[cc];
}

// ---------------------------------------------------------------------------
extern "C" void kernel_launch(void* const* d_in, const int* in_sizes, int n_in,
                              void* d_out, int out_size, void* d_ws, size_t ws_size,
                              hipStream_t stream) {
    const float* x   = (const float*)d_in[0];
    const float* rw1 = (const float*)d_in[1];
    const float* rb1 = (const float*)d_in[2];
    const float* rw2 = (const float*)d_in[3];
    const float* rb2 = (const float*)d_in[4];
    const float* emw = (const float*)d_in[5];
    const float* emb = (const float*)d_in[6];
    const float* aiw = (const float*)d_in[7];
    const float* aib = (const float*)d_in[8];
    const float* aow = (const float*)d_in[9];
    const float* aob = (const float*)d_in[10];
    const float* f1w = (const float*)d_in[11];
    const float* f1b = (const float*)d_in[12];
    const float* f2w = (const float*)d_in[13];
    const float* f2b = (const float*)d_in[14];
    const float* l1s = (const float*)d_in[15];
    const float* l1b = (const float*)d_in[16];
    const float* l2s = (const float*)d_in[17];
    const float* l2b = (const float*)d_in[18];
    const float* fcw = (const float*)d_in[19];
    const float* fcb = (const float*)d_in[20];
    float* out = (float*)d_out;

    char* p = (char*)d_ws;
    auto alloc = [&](size_t bytes) { char* r = p; p += (bytes + 255) & ~(size_t)255; return r; };
    bf16*  biasb = (bf16*)alloc((size_t)CB*CH*CS*CS*2);    // 16.78 MB
    float* h     = (float*)alloc((size_t)CB*CS*CD*4);      // 4.19 MB
    bf16*  hb    = (bf16*)alloc((size_t)CB*CS*CD*2);       // 2.10 MB
    bf16*  qkvb  = (bf16*)alloc((size_t)CB*CS*3*CD*2);     // 6.29 MB
    bf16*  vtb   = (bf16*)alloc((size_t)CB*CH*CDH*CS*2);   // 2.10 MB
    bf16*  attb  = (bf16*)alloc((size_t)CB*CS*CD*2);       // 2.10 MB
    float* tmp   = (float*)alloc((size_t)CB*CS*CD*4);      // 4.19 MB
    bf16*  ffb   = (bf16*)alloc((size_t)CB*CS*CDFF*2);     // 8.39 MB
    bf16*  wl    = (bf16*)alloc((size_t)3145728*2);        // 6.29 MB
    float* rep   = (float*)alloc((size_t)CB*CD*4);
    float* ts    = (float*)alloc(CB*CS*4);
    float* fs    = (float*)alloc(CB*CS*4);

    const int M = CB*CS;  // 2048

    k_standardize<<<dim3(CB,2), 256, 0, stream>>>(x, ts, fs);
    k_relpos<<<(CB*CS*CS)/256, 256, 0, stream>>>(ts, fs, rw1, rb1, rw2, rb2, biasb);
    k_embed<<<(M*CD)/256, 256, 0, stream>>>(x, emw, emb, h, hb);

    for (int l = 0; l < CL; l++) {
        const bf16* wl_aiw = wl;
        const bf16* wl_aow = wl + 786432;
        const bf16* wl_f1w = wl + 1048576;
        const bf16* wl_f2w = wl + 2097152;
        k_wconv<<<1536, 256, 0, stream>>>(aiw + (size_t)l*786432, aow + (size_t)l*262144,
                                          f1w + (size_t)l*1048576, f2w + (size_t)l*1048576, wl);
        // qkv = h @ aiw^T + aib
        k_mm<128,128,0><<<dim3(12,16), 256, 0, stream>>>(hb, CD, wl_aiw, CD,
                                                         aib + (size_t)l*3*CD, qkvb, nullptr, 3*CD, CD);
        // V transpose, fused attention
        k_vt<<<dim3(CS/64, CB*CH), 256, 0, stream>>>(qkvb, vtb);
        k_attn_fused<<<dim3(CS/64, CB*CH), 256, 0, stream>>>(qkvb, vtb, biasb, attb);
        // out projection -> tmp (f32)
        k_mm<64,64,2><<<dim3(8,32), 256, 0, stream>>>(attb, CD, wl_aow, CD,
                                                      aob + (size_t)l*CD, nullptr, tmp, CD, CD);
        k_ln<<<M, 256, 0, stream>>>(h, tmp, l1s + (size_t)l*CD, l1b + (size_t)l*CD, hb);
        // ff1 (relu)
        k_mm<128,128,1><<<dim3(16,16), 256, 0, stream>>>(hb, CD, wl_f1w, CD,
                                                         f1b + (size_t)l*CDFF, ffb, nullptr, CDFF, CD);
        // ff2 -> tmp (f32)
        k_mm<64,64,2><<<dim3(8,32), 256, 0, stream>>>(ffb, CDFF, wl_f2w, CDFF,
                                                      f2b + (size_t)l*CD, nullptr, tmp, CD, CDFF);
        k_ln<<<M, 256, 0, stream>>>(h, tmp, l2s + (size_t)l*CD, l2b + (size_t)l*CD, hb);
    }

    k_pool<<<dim3(CB, CD/64), 256, 0, stream>>>(h, rep);
    k_fc<<<dim3(CB, CNC), 64, 0, stream>>>(rep, fcw, fcb, out);
}